// Round 5
// baseline (55.406 us; speedup 1.0000x reference)
//
#include <hip/hip_runtime.h>

// Per-channel piecewise-linear calibration, real part only (out_size == N).
// x_real: [B=4, C=128, H=256, W=256] f32; xp,yp: [C=128, K=101] f32, xp sorted.

#define K_BP    101
#define K_PAD   128
#define NCH     128
#define HW      65536
#define NBINS   512
#define BLK     256
#define BATCH   4                      // f32x4 loads in flight per thread
#define OUTER   2
#define CPB     (BLK * 4 * BATCH * OUTER)   // 8192 elements per block

typedef float f32x4 __attribute__((ext_vector_type(4)));

__device__ __forceinline__ int bsearch_right(float v, const float* __restrict__ xp_s) {
    // count(xp <= v) over the 128-padded (+inf) array, then segment clamp.
    int lo = 0;
    #pragma unroll
    for (int step = 64; step >= 1; step >>= 1) {
        lo += (xp_s[lo + step - 1] <= v) ? step : 0;
    }
    int j = lo - 1;
    j = j < 0 ? 0 : j;
    j = j > (K_BP - 2) ? (K_BP - 2) : j;
    return j;
}

__device__ __forceinline__ float pwl_eval(float x, float xmin, float invw,
                                          const float4* __restrict__ seg_s,
                                          const unsigned char* __restrict__ lut) {
    int bin = (int)((x - xmin) * invw);
    bin = bin < 0 ? 0 : bin;
    bin = bin > (NBINS - 1) ? (NBINS - 1) : bin;
    int j = (int)lut[bin];
    float4 s = seg_s[j];                 // (x0, y0, slope, _)
    // forward fix-up: lut hint is (up to an ulp at bin edges) a lower bound
    while (j < (K_BP - 2) && x >= seg_s[j + 1].x) { ++j; s = seg_s[j]; }
    // backward guard against bin-boundary FP rounding
    while (j > 0 && x < s.x) { --j; s = seg_s[j]; }
    return fmaf(x - s.x, s.z, s.y);
}

__global__ __launch_bounds__(BLK) void pwl_real_kernel(
    const float* __restrict__ xr,
    const float* __restrict__ xp, const float* __restrict__ yp,
    float* __restrict__ out)
{
    __shared__ float         xp_s[K_PAD];
    __shared__ float4        seg_s[K_BP - 1];
    __shared__ unsigned char lut[NBINS];

    const int t     = threadIdx.x;
    const int bid   = blockIdx.x;
    const int plane = bid >> 3;            // 8 blocks per (b,c) plane
    const int chunk = bid & 7;
    const int c     = plane & (NCH - 1);
    const unsigned int base = (unsigned int)plane * HW + (unsigned int)chunk * CPB;

    // Stage breakpoints (+inf pad so count(xp<=v) ignores the pad).
    if (t < K_PAD) {
        xp_s[t] = (t < K_BP) ? xp[c * K_BP + t] : __builtin_inff();
    }
    __syncthreads();

    // Per-segment (x0, y0, slope): same arithmetic as the reference.
    if (t < K_BP - 1) {
        float y0 = yp[c * K_BP + t];
        float y1 = yp[c * K_BP + t + 1];
        float x0 = xp_s[t];
        float x1 = xp_s[t + 1];
        seg_s[t] = make_float4(x0, y0, (y1 - y0) / (x1 - x0), 0.0f);
    }

    const float xmin = xp_s[0];
    const float xmax = xp_s[K_BP - 1];
    const float w    = (xmax - xmin) * (1.0f / NBINS);
    const float invw = (float)NBINS / (xmax - xmin);

    // Segment-hint LUT: lut[b] = segment containing the bin's left edge.
    #pragma unroll
    for (int b = t; b < NBINS; b += BLK) {
        float bl = fmaf((float)b, w, xmin);
        lut[b] = (unsigned char)bsearch_right(bl, xp_s);
    }
    __syncthreads();

    #pragma unroll
    for (int ot = 0; ot < OUTER; ++ot) {
        // Issue BATCH independent 16B loads before any dependent eval (MLP).
        f32x4 v[BATCH];
        #pragma unroll
        for (int b = 0; b < BATCH; ++b) {
            const unsigned int g = base + ((unsigned int)(ot * BATCH + b) * BLK + t) * 4;
            v[b] = *reinterpret_cast<const f32x4*>(xr + g);
        }
        #pragma unroll
        for (int b = 0; b < BATCH; ++b) {
            f32x4 o;
            o.x = pwl_eval(v[b].x, xmin, invw, seg_s, lut);
            o.y = pwl_eval(v[b].y, xmin, invw, seg_s, lut);
            o.z = pwl_eval(v[b].z, xmin, invw, seg_s, lut);
            o.w = pwl_eval(v[b].w, xmin, invw, seg_s, lut);
            const unsigned int g = base + ((unsigned int)(ot * BATCH + b) * BLK + t) * 4;
            *reinterpret_cast<f32x4*>(out + g) = o;
        }
    }
}

extern "C" void kernel_launch(void* const* d_in, const int* in_sizes, int n_in,
                              void* d_out, int out_size, void* d_ws, size_t ws_size,
                              hipStream_t stream) {
    const float* xr = (const float*)d_in[0];
    const float* xp = (const float*)d_in[2];
    const float* yp = (const float*)d_in[3];
    float* out = (float*)d_out;

    const long long N = (long long)in_sizes[0];   // 33,554,432
    const int blocks = (int)(N / CPB);            // 4096
    pwl_real_kernel<<<dim3(blocks), dim3(BLK), 0, stream>>>(xr, xp, yp, out);
}

// Round 6
// 50.926 us; speedup vs baseline: 1.0880x; 1.0880x over previous
//
#include <hip/hip_runtime.h>

// Per-channel piecewise-linear calibration, real part only (out_size == N).
// x_real: [B=4, C=128, H=256, W=256] f32; xp,yp: [C=128, K=101] f32, xp sorted.
//
// LDS-throughput-optimized: exact-lower-bound segment LUT (forward-only fixup),
// SoA 4/8-byte LDS reads, y = a*x + b evaluation (2 LDS values per element).

#define K_BP    101
#define K_PAD   128
#define NCH     128
#define HW      65536
#define BLK     256
#define NBINS   1024
#define BPT     (NBINS / BLK)          // 4 bins built per thread
#define CPB     4096                   // elements per block (16 blocks/plane)
#define ITERS   (CPB / (BLK * 4))      // 4 iters, one f32x4 per thread per iter
#define MARGIN  1e-5f                  // > worst-case bin-map rounding (~2e-6)

typedef float f32x4 __attribute__((ext_vector_type(4)));

__global__ __launch_bounds__(BLK) void pwl_real_kernel(
    const float* __restrict__ xr,
    const float* __restrict__ xp, const float* __restrict__ yp,
    float* __restrict__ out)
{
    __shared__ float         xp_s[K_PAD];      // +inf padded breakpoints
    __shared__ float2        ab_s[K_BP - 1];   // (a, b): y = a*x + b per segment
    __shared__ unsigned char lut[NBINS];       // lower-bound segment per bin

    const int t     = threadIdx.x;
    const int bid   = blockIdx.x;
    const int plane = bid >> 4;                // 16 blocks per (b,c) plane
    const int chunk = bid & 15;
    const int c     = plane & (NCH - 1);
    const unsigned int base = (unsigned int)plane * HW + (unsigned int)chunk * CPB;

    if (t < K_PAD) {
        xp_s[t] = (t < K_BP) ? xp[c * K_BP + t] : __builtin_inff();
    }
    __syncthreads();

    // Per-segment a = (y1-y0)/(x1-x0) (ref arithmetic), b = y0 - x0*a.
    if (t < K_BP - 1) {
        float x0 = xp_s[t], x1 = xp_s[t + 1];
        float y0 = yp[c * K_BP + t], y1 = yp[c * K_BP + t + 1];
        float a  = (y1 - y0) / (x1 - x0);
        ab_s[t]  = make_float2(a, fmaf(-x0, a, y0));
    }

    const float xmin = xp_s[0];
    const float xmax = xp_s[K_BP - 1];
    const float w    = (xmax - xmin) * (1.0f / NBINS);
    const float invw = (float)NBINS / (xmax - xmin);

    // Build LUT: lut[b] = clamp(count(xp <= left_edge(b) - MARGIN) - 1, 0, 99).
    // Thread t owns bins [4t, 4t+4): one binary search, then monotone walks.
    {
        const int b0 = t * BPT;
        float v = fmaf((float)b0, w, xmin) - MARGIN;
        int j = 0;
        #pragma unroll
        for (int step = 64; step >= 1; step >>= 1) {
            j += (xp_s[j + step - 1] <= v) ? step : 0;
        }
        j -= 1;
        j = j < 0 ? 0 : j;
        j = j > (K_BP - 2) ? (K_BP - 2) : j;
        lut[b0] = (unsigned char)j;
        #pragma unroll
        for (int i = 1; i < BPT; ++i) {
            float vi = fmaf((float)(b0 + i), w, xmin) - MARGIN;
            while (j < (K_BP - 2) && xp_s[j + 1] <= vi) ++j;
            lut[b0 + i] = (unsigned char)j;
        }
    }
    __syncthreads();

    #pragma unroll
    for (int it = 0; it < ITERS; ++it) {
        const unsigned int g = base + ((unsigned int)it * BLK + t) * 4;
        f32x4 v = *reinterpret_cast<const f32x4*>(xr + g);
        f32x4 o;
        #pragma unroll
        for (int e = 0; e < 4; ++e) {
            float x = v[e];
            int bin = (int)((x - xmin) * invw);
            bin = bin < 0 ? 0 : bin;
            bin = bin > (NBINS - 1) ? (NBINS - 1) : bin;
            int j = (int)lut[bin];
            // Forward-only fixup: hint is a provable lower bound on the segment.
            while (j < (K_BP - 2) && x >= xp_s[j + 1]) ++j;
            float2 ab = ab_s[j];
            o[e] = fmaf(x, ab.x, ab.y);
        }
        *reinterpret_cast<f32x4*>(out + g) = o;
    }
}

extern "C" void kernel_launch(void* const* d_in, const int* in_sizes, int n_in,
                              void* d_out, int out_size, void* d_ws, size_t ws_size,
                              hipStream_t stream) {
    const float* xr = (const float*)d_in[0];
    const float* xp = (const float*)d_in[2];
    const float* yp = (const float*)d_in[3];
    float* out = (float*)d_out;

    const long long N = (long long)in_sizes[0];   // 33,554,432
    const int blocks = (int)(N / CPB);            // 8192
    pwl_real_kernel<<<dim3(blocks), dim3(BLK), 0, stream>>>(xr, xp, yp, out);
}